// Round 1
// baseline (341.338 us; speedup 1.0000x reference)
//
#include <hip/hip_runtime.h>
#include <math.h>

// GaussianModel projection pre-pass.
// Reference (JAX):
//   pos_view = clip((p - t) @ R^T, -100, 100)
//   valid    = 0.1 < pos_view.z < 10
//   z        = clip(pos_view.z, 0.1, 10)
//   x        = clip(pv.x*FX/z + W/2, -1000, W+1000)
//   y        = clip(-(pv.y*FY/z) + H/2, -1000, H+1000)
//   cov2d    = [[clip(sx^2+1e-4,1e-6,1e6), 1e-6],[1e-6, clip(sy^2+1e-4,...)]]
//              where sx = max(scale.x,1e-3)*FX/z, sy = max(scale.y,1e-3)*FY/z
//   colors clipped to [0,1]; opacity -> sigmoid; mask -> 1.0/0.0
// Outputs concatenated flat (float32):
//   [0,3N) proj | [3N,7N) cov2d | [7N,10N) colors | [10N,11N) opa | [11N,12N) mask

#define FXc 500.0f

__global__ __launch_bounds__(256) void gs_project(
    const float* __restrict__ pos,
    const float* __restrict__ scl,
    const float* __restrict__ col,
    const float* __restrict__ opa,
    const float* __restrict__ vm,
    const int* __restrict__ pw,
    const int* __restrict__ ph,
    float* __restrict__ out,
    int N)
{
    int i = blockIdx.x * blockDim.x + threadIdx.x;
    if (i >= N) return;

    // viewmat row-major 4x4; R = vm[:3,:3], t = vm[:3,3]. Uniform -> s_loads.
    float r00 = vm[0], r01 = vm[1], r02 = vm[2],  t0 = vm[3];
    float r10 = vm[4], r11 = vm[5], r12 = vm[6],  t1 = vm[7];
    float r20 = vm[8], r21 = vm[9], r22 = vm[10], t2 = vm[11];
    float W = (float)(*pw), H = (float)(*ph);

    float px = pos[3*i + 0], py = pos[3*i + 1], pz = pos[3*i + 2];
    float dx = px - t0, dy = py - t1, dz = pz - t2;
    float v0 = r00*dx + r01*dy + r02*dz;
    float v1 = r10*dx + r11*dy + r12*dz;
    float v2 = r20*dx + r21*dy + r22*dz;
    v0 = fminf(fmaxf(v0, -100.0f), 100.0f);
    v1 = fminf(fmaxf(v1, -100.0f), 100.0f);
    v2 = fminf(fmaxf(v2, -100.0f), 100.0f);

    float valid = (v2 > 0.1f && v2 < 10.0f) ? 1.0f : 0.0f;
    float z   = fminf(fmaxf(v2, 0.1f), 10.0f);
    float fxz = FXc / z;   // FX == FY == 500

    float x = fminf(fmaxf(v0 * fxz + 0.5f * W, -1000.0f), W + 1000.0f);
    float y = fminf(fmaxf(0.5f * H - v1 * fxz, -1000.0f), H + 1000.0f);

    // proj_points
    out[3*i + 0] = x;
    out[3*i + 1] = y;
    out[3*i + 2] = v2;

    // cov2d (float4 store; base 3N floats is 16B-aligned, N % 4 == 0)
    float sx = fmaxf(scl[3*i + 0], 0.001f) * fxz;
    float sy = fmaxf(scl[3*i + 1], 0.001f) * fxz;
    float c00 = fminf(fmaxf(sx*sx + 1e-4f, 1e-6f), 1e6f);
    float c11 = fminf(fmaxf(sy*sy + 1e-4f, 1e-6f), 1e6f);
    *reinterpret_cast<float4*>(out + (size_t)3*N + 4*(size_t)i) =
        make_float4(c00, 1e-6f, 1e-6f, c11);

    // colors clipped
    const float* cp = col + 3*(size_t)i;
    float* co = out + (size_t)7*N + 3*(size_t)i;
    co[0] = fminf(fmaxf(cp[0], 0.0f), 1.0f);
    co[1] = fminf(fmaxf(cp[1], 0.0f), 1.0f);
    co[2] = fminf(fmaxf(cp[2], 0.0f), 1.0f);

    // sigmoid opacity + mask
    float o = opa[i];
    out[(size_t)10*N + i] = 1.0f / (1.0f + expf(-o));
    out[(size_t)11*N + i] = valid;
}

extern "C" void kernel_launch(void* const* d_in, const int* in_sizes, int n_in,
                              void* d_out, int out_size, void* d_ws, size_t ws_size,
                              hipStream_t stream) {
    const float* pos = (const float*)d_in[0];
    const float* scl = (const float*)d_in[1];
    // d_in[2] rotations: UNUSED by reference
    const float* col = (const float*)d_in[3];
    const float* opa = (const float*)d_in[4];
    const float* vm  = (const float*)d_in[5];
    // d_in[6] projmat: UNUSED by reference
    const int*   pw  = (const int*)d_in[7];
    const int*   ph  = (const int*)d_in[8];

    int N = in_sizes[0] / 3;
    int blocks = (N + 255) / 256;
    gs_project<<<blocks, 256, 0, stream>>>(pos, scl, col, opa, vm, pw, ph,
                                           (float*)d_out, N);
}